// Round 1
// baseline (440.013 us; speedup 1.0000x reference)
//
#include <hip/hip_runtime.h>

// LengthRegulator: B=32, T=1024, D=384, MAX_LEN=8192
// out0: (B, MAX_LEN, D) f32 gather of x rows per searchsorted(cumsum(duration), frame, 'right')
// out1: (B,) mel_len = cumsum(duration)[:, -1], stored float-coded in d_out tail (harness-verified).

#define LR_B 32
#define LR_T 1024
#define LR_D 384
#define LR_MAXLEN 8192
#define LR_D4 (LR_D / 4)                    // 96 float4 per row
#define LR_BATCH_F4 (LR_MAXLEN * LR_D4)     // 786432 float4 per batch image
#define LR_UNROLL 8
#define LR_BLK 256
#define LR_BLK_F4 (LR_BLK * LR_UNROLL)      // 2048 float4 per block
#define LR_NBLK (LR_BATCH_F4 / LR_BLK_F4)   // 384 blocks per batch, exact

typedef float fx4 __attribute__((ext_vector_type(4)));

// Kernel A: per-batch inclusive scan of durations via wave shuffles.
// Emits mel_len (float-coded for out1, int for device use) and the
// frame -> source-offset table for the VALID prefix only:
//   src_ws[b*MAX_LEN + f] = (b*T + token)*D4   for f < mel_len[b]
// (frames >= mel_len are never read by the consumers below.)
__global__ __launch_bounds__(LR_T) void lr_scan_scatter(
    const int* __restrict__ dur,     // (B, T)
    int* __restrict__ src_ws,        // (B, MAX_LEN)
    int* __restrict__ mel_i,         // (B,) int copy for device consumers
    float* __restrict__ mel_out)     // (B,) float-coded int for out1
{
    const int b = blockIdx.x;
    const int t = threadIdx.x;
    const int lane = t & 63;
    const int wave = t >> 6;         // 16 waves

    const int d = dur[b * LR_T + t];

    // Inclusive scan within the wave (6 shuffle steps, no barriers)
    int v = d;
    #pragma unroll
    for (int off = 1; off < 64; off <<= 1) {
        int n = __shfl_up(v, off, 64);
        if (lane >= off) v += n;
    }

    __shared__ int wsum[16];
    __shared__ int woff[16];
    if (lane == 63) wsum[wave] = v;
    __syncthreads();

    // Scan the 16 wave sums inside wave 0
    if (wave == 0 && lane < 16) {
        int s = wsum[lane];
        #pragma unroll
        for (int off = 1; off < 16; off <<= 1) {
            int n = __shfl_up(s, off, 64);
            if (lane >= off) s += n;
        }
        woff[lane] = s;              // inclusive scan of wave sums
    }
    __syncthreads();

    const int base  = (wave == 0) ? 0 : woff[wave - 1];
    const int end   = base + v;      // inclusive csum at token t
    const int start = end - d;
    const int total = woff[15];      // mel_len, <= 7*1024 < MAX_LEN

    if (t == 0) { mel_out[b] = (float)total; mel_i[b] = total; }

    int* row = src_ws + b * LR_MAXLEN;
    const int src_off = (b * LR_T + t) * LR_D4;   // float4 offset of token row
    for (int f = start; f < end; ++f) row[f] = src_off;   // <= 7 iterations
}

// Kernel B1: valid-prefix gather (frames < mel_len[b]). NT stores keep the
// write stream out of L2 so x (48 MB, reused ~3.5x) stays cached.
// Grid: (LR_NBLK, LR_B). Blocks entirely past mel exit immediately.
__global__ __launch_bounds__(LR_BLK) void lr_gather_valid(
    const fx4* __restrict__ x,       // (B, T, D4)
    const int* __restrict__ src_ws,  // (B, MAX_LEN)
    const int* __restrict__ mel_i,   // (B,)
    fx4* __restrict__ out)           // (B, MAX_LEN, D4)
{
    const int b = blockIdx.y;
    const int mel = mel_i[b];
    const unsigned fb0 = blockIdx.x * (unsigned)LR_BLK_F4;      // f4 offset in batch
    if ((int)(fb0 / LR_D4) >= mel) return;                      // fully invalid block

    const int* __restrict__ row = src_ws + b * LR_MAXLEN;
    fx4* __restrict__ outb = out + (size_t)b * LR_BATCH_F4;
    const unsigned base = fb0 + threadIdx.x;
    const unsigned lastf = (fb0 + LR_BLK_F4 - 1) / LR_D4;

    if ((int)lastf < mel) {
        // Fully valid block: no per-element predicate.
        #pragma unroll
        for (int u = 0; u < LR_UNROLL; ++u) {
            const unsigned g = base + u * LR_BLK;
            const unsigned frame = g / LR_D4;                   // magic-mul div by 96
            const unsigned e = g - frame * LR_D4;
            const int s = row[frame];
            __builtin_nontemporal_store(x[(unsigned)s + e], outb + g);
        }
    } else {
        // Boundary block (~1 per batch): predicated.
        #pragma unroll
        for (int u = 0; u < LR_UNROLL; ++u) {
            const unsigned g = base + u * LR_BLK;
            const unsigned frame = g / LR_D4;
            if ((int)frame < mel) {
                const unsigned e = g - frame * LR_D4;
                const int s = row[frame];
                __builtin_nontemporal_store(x[(unsigned)s + e], outb + g);
            }
        }
    }
}

// Kernel B2: tail zero-fill (frames >= mel_len[b]). Pure write stream with
// PLAIN dwordx4 stores -- this is exactly what rocclr's fillBuffer does at
// 6.36 TB/s on this chip; NT bought nothing here (no x reads to protect).
// Grid: (LR_NBLK, LR_B). Blocks entirely before mel exit immediately.
__global__ __launch_bounds__(LR_BLK) void lr_zero_tail(
    const int* __restrict__ mel_i,   // (B,)
    fx4* __restrict__ out)           // (B, MAX_LEN, D4)
{
    const int b = blockIdx.y;
    const int mel = mel_i[b];
    const unsigned fb0 = blockIdx.x * (unsigned)LR_BLK_F4;
    const unsigned lastf = (fb0 + LR_BLK_F4 - 1) / LR_D4;
    if ((int)lastf < mel) return;                               // fully valid block

    fx4* __restrict__ outb = out + (size_t)b * LR_BATCH_F4;
    const unsigned base = fb0 + threadIdx.x;
    const fx4 z = (fx4)(0.f, 0.f, 0.f, 0.f);

    if ((int)(fb0 / LR_D4) >= mel) {
        // Fully invalid block: unconditional streaming stores.
        #pragma unroll
        for (int u = 0; u < LR_UNROLL; ++u) {
            outb[base + u * LR_BLK] = z;
        }
    } else {
        // Boundary block: predicated.
        #pragma unroll
        for (int u = 0; u < LR_UNROLL; ++u) {
            const unsigned g = base + u * LR_BLK;
            if ((int)(g / LR_D4) >= mel) outb[g] = z;
        }
    }
}

extern "C" void kernel_launch(void* const* d_in, const int* in_sizes, int n_in,
                              void* d_out, int out_size, void* d_ws, size_t ws_size,
                              hipStream_t stream) {
    const float* x   = (const float*)d_in[0];
    const int*   dur = (const int*)d_in[1];
    // d_in[2] = max_len (scalar on device) -- constant 8192 for this problem.

    float* out0 = (float*)d_out;                          // (B, MAX_LEN, D)
    float* mel  = out0 + (size_t)LR_B * LR_MAXLEN * LR_D; // (B,) tail
    int*   src_ws = (int*)d_ws;                           // B*MAX_LEN ints = 1 MB
    int*   mel_i  = src_ws + LR_B * LR_MAXLEN;            // (B,) ints after table

    lr_scan_scatter<<<LR_B, LR_T, 0, stream>>>(dur, src_ws, mel_i, mel);

    const dim3 grid(LR_NBLK, LR_B);
    lr_gather_valid<<<grid, LR_BLK, 0, stream>>>(
        (const fx4*)x, src_ws, mel_i, (fx4*)out0);
    lr_zero_tail<<<grid, LR_BLK, 0, stream>>>(mel_i, (fx4*)out0);
}